// Round 6
// baseline (251.552 us; speedup 1.0000x reference)
//
#include <hip/hip_runtime.h>
#include <math.h>

#define NPTS 2048
#define BATCH 16
#define KNN 16
#define HID 128
#define CAP 128        // compacted-candidate capacity per query

typedef __attribute__((ext_vector_type(8))) short bf16x8;
typedef __attribute__((ext_vector_type(4))) float f32x4;

__device__ inline unsigned short f2bf(float f) {    // RNE f32 -> bf16 bits
    unsigned u = __float_as_uint(f);
    return (unsigned short)((u + 0x7FFFu + ((u >> 16) & 1u)) >> 16);
}
__device__ inline float bflo(unsigned v) { return __uint_as_float(v << 16); }
__device__ inline float bfhi(unsigned v) { return __uint_as_float(v & 0xFFFF0000u); }

// ---------------------------------------------------------------------------
// kNN v2: 2 queries per wave (each candidate float4 LDS read feeds both),
// prefix-scan compaction (no per-candidate ballots), uint2-packed survivors,
// fused neighbor-position aggregation (writes aggpc for layer 1).
// key = float_bits(d2 + 16) (monotone); set-selection: output ORDER is
// irrelevant downstream (only summed), ties broken by smaller index.
// ---------------------------------------------------------------------------

// Exact fallback for m > CAP (probability ~0; correctness only).
#define KNN_FALLBACK(KEY, OUTP, AX, AY, AZ)                                    \
  {                                                                            \
    unsigned T = 0;                                                            \
    for (int bit = 31; bit >= 0; --bit) {                                      \
      unsigned trial = T | (1u << bit);                                        \
      int cnt = 0;                                                             \
      _Pragma("unroll") for (int t = 0; t < 32; ++t) cnt += (KEY[t] < trial);  \
      _Pragma("unroll") for (int off = 32; off; off >>= 1)                     \
          cnt += __shfl_xor(cnt, off, 64);                                     \
      if (cnt < KNN) T = trial;                                                \
    }                                                                          \
    unsigned bs = 0;                                                           \
    for (int t = 0; t < 32; ++t) {                                             \
      bool p1 = KEY[t] < T;                                                    \
      unsigned long long mk = __ballot(p1);                                    \
      if (mk) {                                                                \
        unsigned pre = __builtin_amdgcn_mbcnt_hi((unsigned)(mk >> 32),         \
                       __builtin_amdgcn_mbcnt_lo((unsigned)mk, 0));            \
        if (p1) { OUTP[bs + pre] = t * 64 + lane;                              \
                  float4 q = pts[t * 64 + lane];                               \
                  AX += q.x; AY += q.y; AZ += q.z; }                           \
        bs += (unsigned)__popcll(mk);                                          \
      }                                                                        \
    }                                                                          \
    for (int t = 0; t < 32 && bs < KNN; ++t) {                                 \
      bool p2 = KEY[t] == T;                                                   \
      unsigned long long mk = __ballot(p2);                                    \
      if (mk) {                                                                \
        unsigned pre = __builtin_amdgcn_mbcnt_hi((unsigned)(mk >> 32),         \
                       __builtin_amdgcn_mbcnt_lo((unsigned)mk, 0));            \
        unsigned pos = bs + pre;                                               \
        if (p2 && pos < KNN) { OUTP[pos] = t * 64 + lane;                      \
                  float4 q = pts[t * 64 + lane];                               \
                  AX += q.x; AY += q.y; AZ += q.z; }                           \
        bs += (unsigned)__popcll(mk);                                          \
      }                                                                        \
    }                                                                          \
  }

// Select set-of-16 among survivors (<= T0V), write indices + agg position sum.
#define PROCESS_QUERY(KEY, T0V, QSLOT, OUTP, AGGIDX)                           \
  {                                                                            \
    int cnt = 0;                                                               \
    _Pragma("unroll") for (int t = 0; t < 32; ++t) cnt += (KEY[t] <= T0V);     \
    int inc = cnt;                                                             \
    _Pragma("unroll") for (int d = 1; d < 64; d <<= 1) {                       \
      int o = __shfl_up(inc, d, 64);                                           \
      if (lane >= d) inc += o;                                                 \
    }                                                                          \
    const int m = __shfl(inc, 63, 64);                                         \
    float ax = 0.f, ay = 0.f, az = 0.f;                                        \
    if (m <= CAP) {                                                            \
      unsigned pos = (unsigned)(inc - cnt);                                    \
      _Pragma("unroll") for (int t = 0; t < 32; ++t)                           \
        if (KEY[t] <= T0V) {                                                   \
          cand[w][QSLOT][pos] = make_uint2(KEY[t], (unsigned)(t * 64 + lane)); \
          pos++;                                                               \
        }                                                                      \
      __threadfence_block();                                                   \
      uint2 e0 = (lane < m) ? cand[w][QSLOT][lane]                             \
                            : make_uint2(0xFFFFFFFFu, 0xFFFFFFFFu);            \
      int r0 = 0;                                                              \
      if (m <= 64) {                                                           \
        for (int jj = 0; jj < m; ++jj) {                                       \
          uint2 cj = cand[w][QSLOT][jj];                                       \
          r0 += (cj.x < e0.x) || (cj.x == e0.x && cj.y < e0.y);                \
        }                                                                      \
        if (lane < m && r0 < KNN) {                                            \
          OUTP[r0] = (int)e0.y;                                                \
          float4 q = pts[e0.y]; ax = q.x; ay = q.y; az = q.z;                  \
        }                                                                      \
      } else {                                                                 \
        uint2 e1 = (lane + 64 < m) ? cand[w][QSLOT][lane + 64]                 \
                                   : make_uint2(0xFFFFFFFFu, 0xFFFFFFFFu);     \
        int r1 = 0;                                                            \
        for (int jj = 0; jj < m; ++jj) {                                       \
          uint2 cj = cand[w][QSLOT][jj];                                       \
          r0 += (cj.x < e0.x) || (cj.x == e0.x && cj.y < e0.y);                \
          r1 += (cj.x < e1.x) || (cj.x == e1.x && cj.y < e1.y);                \
        }                                                                      \
        if (lane < m && r0 < KNN) {                                            \
          OUTP[r0] = (int)e0.y;                                                \
          float4 q = pts[e0.y]; ax = q.x; ay = q.y; az = q.z;                  \
        }                                                                      \
        if (lane + 64 < m && r1 < KNN) {                                       \
          OUTP[r1] = (int)e1.y;                                                \
          float4 q = pts[e1.y]; ax += q.x; ay += q.y; az += q.z;               \
        }                                                                      \
      }                                                                        \
    } else {                                                                   \
      KNN_FALLBACK(KEY, OUTP, ax, ay, az)                                      \
    }                                                                          \
    _Pragma("unroll") for (int o2 = 32; o2; o2 >>= 1) {                        \
      ax += __shfl_xor(ax, o2, 64);                                            \
      ay += __shfl_xor(ay, o2, 64);                                            \
      az += __shfl_xor(az, o2, 64);                                            \
    }                                                                          \
    if (lane == 0) aggpc[AGGIDX] = make_float4(ax, ay, az, 0.f);               \
  }

__global__ __launch_bounds__(512) void knn_kernel(const float* __restrict__ pc,
                                                  int* __restrict__ nbr,
                                                  float4* __restrict__ aggpc)
{
    __shared__ __align__(16) float4 pts[NPTS];        // 32 KB
    __shared__ uint2 cand[8][2][CAP];                 // 16 KB

    const int b = blockIdx.x >> 7;                    // 128 blocks per batch
    const int rblk = blockIdx.x & 127;
    const float* p = pc + (size_t)b * NPTS * 3;

    for (int t = threadIdx.x; t < NPTS; t += 512) {
        float x = p[t * 3 + 0], y = p[t * 3 + 1], z = p[t * 3 + 2];
        pts[t] = make_float4(x, y, z, x * x + y * y + z * z);
    }
    __syncthreads();

    const int w = threadIdx.x >> 6;
    const int lane = threadIdx.x & 63;
    const int i0 = rblk * 16 + w * 2;                 // query rows (local)
    const int i1 = i0 + 1;
    const float4 p0 = pts[i0];
    const float4 p1 = pts[i1];
    const float pw0 = p0.w + 16.f;
    const float pw1 = p1.w + 16.f;

    // ---- phase 1: 32 candidates/lane, keys for BOTH queries per load ------
    unsigned key0[32], key1[32];
    unsigned km0 = 0xFFFFFFFFu, km1 = 0xFFFFFFFFu;
    #pragma unroll
    for (int t = 0; t < 32; ++t) {
        float4 c = pts[t * 64 + lane];
        float d0 = fmaf(-2.0f, fmaf(p0.x, c.x, fmaf(p0.y, c.y, p0.z * c.z)),
                        pw0 + c.w);
        float d1 = fmaf(-2.0f, fmaf(p1.x, c.x, fmaf(p1.y, c.y, p1.z * c.z)),
                        pw1 + c.w);
        key0[t] = __float_as_uint(d0);
        key1[t] = __float_as_uint(d1);
        km0 = min(km0, key0[t]);
        km1 = min(km1, key1[t]);
    }

    // ---- phase 2/3: bitonic sort of 64 lane-mins (both queries, ILP) ------
    unsigned v0 = km0, v1 = km1;
    #pragma unroll
    for (int k = 2; k <= 64; k <<= 1) {
        #pragma unroll
        for (int j = k >> 1; j > 0; j >>= 1) {
            unsigned o0 = (unsigned)__shfl_xor((int)v0, j, 64);
            unsigned o1 = (unsigned)__shfl_xor((int)v1, j, 64);
            bool sel = ((lane & k) == 0) == ((lane & j) == 0);
            v0 = sel ? min(v0, o0) : max(v0, o0);
            v1 = sel ? min(v1, o1) : max(v1, o1);
        }
    }
    const unsigned T00 = (unsigned)__shfl((int)v0, 15, 64);
    const unsigned T01 = (unsigned)__shfl((int)v1, 15, 64);
    // >=16 candidates <= T0 (the 16 smallest lane-mins themselves) and
    // T0 >= true 16th-smallest => {key <= T0} is a superset of the top-16.

    int* out0 = nbr + ((size_t)b * NPTS + i0) * KNN;
    int* out1 = nbr + ((size_t)b * NPTS + i1) * KNN;
    const size_t g0 = (size_t)b * NPTS + i0;
    const size_t g1 = g0 + 1;

    PROCESS_QUERY(key0, T00, 0, out0, g0)
    PROCESS_QUERY(key1, T01, 1, out1, g1)
}

// ---------------------------------------------------------------------------
// Layer 1: 3 -> 128 on precomputed aggpc. Thread per (p, h). Gather-free.
// ---------------------------------------------------------------------------
__global__ __launch_bounds__(256) void layer1_kernel(
    const float* __restrict__ pc, const float4* __restrict__ aggpc,
    const float* __restrict__ W1r, const float* __restrict__ b1,
    const float* __restrict__ W1s, unsigned short* __restrict__ x1)
{
    int gid = blockIdx.x * 256 + threadIdx.x;     // < 32768*128
    int p = gid >> 7;
    int h = gid & 127;
    float4 a = aggpc[p];
    float xx = pc[(size_t)p * 3 + 0];
    float xy = pc[(size_t)p * 3 + 1];
    float xz = pc[(size_t)p * 3 + 2];
    float acc = b1[h];
    acc += W1r[h * 3 + 0] * a.x + W1r[h * 3 + 1] * a.y + W1r[h * 3 + 2] * a.z;
    acc += W1s[h * 3 + 0] * xx + W1s[h * 3 + 1] * xy + W1s[h * 3 + 2] * xz;
    x1[gid] = f2bf(fmaxf(acc, 0.f));
}

// ---------------------------------------------------------------------------
// Weight conversion: 4 x [128x128] f32 -> bf16.
// ---------------------------------------------------------------------------
__global__ __launch_bounds__(256) void wcvt_kernel(
    const float* __restrict__ a, const float* __restrict__ b,
    const float* __restrict__ c, const float* __restrict__ d,
    unsigned short* __restrict__ out)
{
    int g = blockIdx.x * 256 + threadIdx.x;       // < 65536
    int m = g >> 14;
    const float* s = (m == 0) ? a : (m == 1) ? b : (m == 2) ? c : d;
    out[g] = f2bf(s[g & 16383]);
}

// ---------------------------------------------------------------------------
// Fused gather + GraphConv via bf16 MFMA.
// Block 512 thr = 8 waves, tile 64 points x 128 h.
// Stage 1: nbr rows -> LDS (padded [64][17]); cooperative gather-sum of
//          16 neighbor rows per point -> bf16 agg tile in LDS [64][136]
//          (pad 136 shorts: staging writes & MFMA reads are 2-way/free).
// Stage 2: wave (32 pt x 32 h) MFMA: A=agg from LDS / A=x from global,
//          B=Wr/Ws rows from global (L1/L2-resident).
// Layouts [measured m89/m91]: A[m=lane&15][k=quad*8+j]; B^T same;
// D: col=lane&15, row=quad*4+reg.
// ---------------------------------------------------------------------------
template <bool RELU, bool OUT_BF16>
__global__ __launch_bounds__(512) void conv_fused(
    const unsigned short* __restrict__ x, const int* __restrict__ nbr,
    const unsigned short* __restrict__ Wr, const unsigned short* __restrict__ Ws,
    const float* __restrict__ bias, void* __restrict__ outv)
{
    __shared__ __align__(16) unsigned short aggs[64][136];   // 17.4 KB
    __shared__ int nbrs[64][17];                             // 4.4 KB
    const int p0 = blockIdx.x * 64;                          // global point base
    const int bt = p0 >> 11;                                 // batch
    const unsigned short* xb = x + ((size_t)bt << 11) * HID; // batch-local rows

    // ---- stage nbr into LDS (coalesced) -----------------------------------
    for (int e = threadIdx.x; e < 64 * KNN; e += 512)
        nbrs[e >> 4][e & 15] = nbr[(size_t)p0 * KNN + e];
    __syncthreads();

    // ---- cooperative gather-sum -> bf16 agg tile --------------------------
    #pragma unroll
    for (int it = 0; it < 2; ++it) {
        int task = it * 512 + threadIdx.x;        // 0..1023
        int pt = task & 63, c8 = task >> 6;       // c8 0..15
        const unsigned short* base = xb + c8 * 8;
        float s[8] = {0, 0, 0, 0, 0, 0, 0, 0};
        #pragma unroll
        for (int t = 0; t < KNN; ++t) {
            int j = nbrs[pt][t];
            uint4 v = *(const uint4*)(base + (size_t)j * HID);
            s[0] += bflo(v.x); s[1] += bfhi(v.x);
            s[2] += bflo(v.y); s[3] += bfhi(v.y);
            s[4] += bflo(v.z); s[5] += bfhi(v.z);
            s[6] += bflo(v.w); s[7] += bfhi(v.w);
        }
        uint4 ov;
        ov.x = (unsigned)f2bf(s[0]) | ((unsigned)f2bf(s[1]) << 16);
        ov.y = (unsigned)f2bf(s[2]) | ((unsigned)f2bf(s[3]) << 16);
        ov.z = (unsigned)f2bf(s[4]) | ((unsigned)f2bf(s[5]) << 16);
        ov.w = (unsigned)f2bf(s[6]) | ((unsigned)f2bf(s[7]) << 16);
        *(uint4*)&aggs[pt][c8 * 8] = ov;
    }
    __syncthreads();

    // ---- MFMA: wave tile 32 pts x 32 h ------------------------------------
    const int wv = threadIdx.x >> 6;
    const int lane = threadIdx.x & 63;
    const int ptw = (wv & 1) * 32;                // 0 / 32
    const int h0w = (wv >> 1) * 32;               // 0 / 32 / 64 / 96
    const int row = lane & 15;
    const int quad = lane >> 4;

    f32x4 acc[2][2];
    #pragma unroll
    for (int i = 0; i < 2; ++i)
        #pragma unroll
        for (int n = 0; n < 2; ++n) acc[i][n] = (f32x4){0, 0, 0, 0};

    // agg @ Wr^T
    #pragma unroll
    for (int kc = 0; kc < 4; ++kc) {
        bf16x8 a0 = *(const bf16x8*)&aggs[ptw + row][quad * 8 + kc * 32];
        bf16x8 a1 = *(const bf16x8*)&aggs[ptw + 16 + row][quad * 8 + kc * 32];
        #pragma unroll
        for (int n = 0; n < 2; ++n) {
            bf16x8 bb = *(const bf16x8*)&Wr[(size_t)(h0w + n * 16 + row) * HID
                                            + quad * 8 + kc * 32];
            acc[0][n] = __builtin_amdgcn_mfma_f32_16x16x32_bf16(a0, bb, acc[0][n], 0, 0, 0);
            acc[1][n] = __builtin_amdgcn_mfma_f32_16x16x32_bf16(a1, bb, acc[1][n], 0, 0, 0);
        }
    }
    // x @ Ws^T
    const unsigned short* xr0 = x + (size_t)(p0 + ptw + row) * HID + quad * 8;
    const unsigned short* xr1 = xr0 + 16 * HID;
    #pragma unroll
    for (int kc = 0; kc < 4; ++kc) {
        bf16x8 a0 = *(const bf16x8*)(xr0 + kc * 32);
        bf16x8 a1 = *(const bf16x8*)(xr1 + kc * 32);
        #pragma unroll
        for (int n = 0; n < 2; ++n) {
            bf16x8 bb = *(const bf16x8*)&Ws[(size_t)(h0w + n * 16 + row) * HID
                                            + quad * 8 + kc * 32];
            acc[0][n] = __builtin_amdgcn_mfma_f32_16x16x32_bf16(a0, bb, acc[0][n], 0, 0, 0);
            acc[1][n] = __builtin_amdgcn_mfma_f32_16x16x32_bf16(a1, bb, acc[1][n], 0, 0, 0);
        }
    }

    // ---- epilogue ---------------------------------------------------------
    #pragma unroll
    for (int n = 0; n < 2; ++n) {
        float bh = bias[h0w + n * 16 + row];
        #pragma unroll
        for (int i = 0; i < 2; ++i) {
            #pragma unroll
            for (int r = 0; r < 4; ++r) {
                int pp = p0 + ptw + i * 16 + quad * 4 + r;
                float vv = acc[i][n][r] + bh;
                if (RELU) vv = fmaxf(vv, 0.f);
                if (OUT_BF16)
                    ((unsigned short*)outv)[(size_t)pp * HID + h0w + n * 16 + row] = f2bf(vv);
                else
                    ((float*)outv)[(size_t)pp * HID + h0w + n * 16 + row] = vv;
            }
        }
    }
}

// ---------------------------------------------------------------------------
extern "C" void kernel_launch(void* const* d_in, const int* in_sizes, int n_in,
                              void* d_out, int out_size, void* d_ws, size_t ws_size,
                              hipStream_t stream)
{
    const float* pc  = (const float*)d_in[0];
    const float* W1r = (const float*)d_in[1];
    const float* b1  = (const float*)d_in[2];
    const float* W1s = (const float*)d_in[3];
    const float* W2r = (const float*)d_in[4];
    const float* b2  = (const float*)d_in[5];
    const float* W2s = (const float*)d_in[6];
    const float* W3r = (const float*)d_in[7];
    const float* b3  = (const float*)d_in[8];
    const float* W3s = (const float*)d_in[9];
    float* out = (float*)d_out;

    char* ws = (char*)d_ws;
    const size_t MB = 1024 * 1024;
    int*            nbr   = (int*)ws;                             // 2 MB
    float4*         aggpc = (float4*)(ws + 2 * MB);               // 512 KB
    unsigned short* x1    = (unsigned short*)(ws + 3 * MB);       // 8.39 MB
    unsigned short* x2    = (unsigned short*)(ws + 3 * MB + 8388608);
    unsigned short* wbf   = (unsigned short*)(ws + 3 * MB + 2 * 8388608);
    unsigned short* w2r = wbf;
    unsigned short* w2s = wbf + 16384;
    unsigned short* w3r = wbf + 32768;
    unsigned short* w3s = wbf + 49152;

    const int NPOINTS = BATCH * NPTS;                             // 32768

    knn_kernel<<<NPOINTS / 16, 512, 0, stream>>>(pc, nbr, aggpc);
    layer1_kernel<<<NPOINTS * HID / 256, 256, 0, stream>>>(
        pc, aggpc, W1r, b1, W1s, x1);
    wcvt_kernel<<<256, 256, 0, stream>>>(W2r, W2s, W3r, W3s, wbf);

    conv_fused<true, true><<<NPOINTS / 64, 512, 0, stream>>>(
        x1, nbr, w2r, w2s, b2, x2);
    conv_fused<false, false><<<NPOINTS / 64, 512, 0, stream>>>(
        x2, nbr, w3r, w3s, b3, out);
}

// Round 7
// 184.678 us; speedup vs baseline: 1.3621x; 1.3621x over previous
//
#include <hip/hip_runtime.h>
#include <math.h>

#define NPTS 2048
#define BATCH 16
#define KNN 16
#define HID 128
#define RPB 8          // rows (queries) per block = waves per block
#define CAP 128        // compacted-candidate capacity per wave

typedef __attribute__((ext_vector_type(8))) short bf16x8;
typedef __attribute__((ext_vector_type(4))) float f32x4;

__device__ inline unsigned short f2bf(float f) {    // RNE f32 -> bf16 bits
    unsigned u = __float_as_uint(f);
    return (unsigned short)((u + 0x7FFFu + ((u >> 16) & 1u)) >> 16);
}
__device__ inline float bflo(unsigned v) { return __uint_as_float(v << 16); }
__device__ inline float bfhi(unsigned v) { return __uint_as_float(v & 0xFFFF0000u); }

// ---------------------------------------------------------------------------
// kNN via threshold selection — R5-proven structure (1 query/wave, ballot
// compaction, 40 VGPR) + fused neighbor-position sum (aggpc) in the tail.
// key = float_bits(d2 + 16) (monotone). Set-selection: neighbor ORDER is
// irrelevant downstream (only summed); ties broken by smaller index.
// ---------------------------------------------------------------------------
__global__ __launch_bounds__(512) void knn_kernel(const float* __restrict__ pc,
                                                  int* __restrict__ nbr,
                                                  float4* __restrict__ aggpc)
{
    __shared__ __align__(16) float4 pts[NPTS];        // x,y,z,|p|^2  (32 KB)
    __shared__ unsigned ckey[RPB][CAP];               // 4 KB
    __shared__ unsigned cidx[RPB][CAP];               // 4 KB

    const int b = blockIdx.x >> 8;                    // 256 blocks per batch
    const int rblk = blockIdx.x & 255;
    const float* p = pc + (size_t)b * NPTS * 3;

    for (int t = threadIdx.x; t < NPTS; t += 512) {
        float x = p[t * 3 + 0], y = p[t * 3 + 1], z = p[t * 3 + 2];
        pts[t] = make_float4(x, y, z, x * x + y * y + z * z);
    }
    __syncthreads();

    const int w = threadIdx.x >> 6;
    const int lane = threadIdx.x & 63;
    const int i = rblk * RPB + w;                     // query row in batch
    const float4 pi = pts[i];

    unsigned key[32];
    #pragma unroll
    for (int t = 0; t < 32; ++t) {
        float4 c = pts[t * 64 + lane];
        float dot = fmaf(pi.x, c.x, fmaf(pi.y, c.y, pi.z * c.z));
        float d2 = fmaf(-2.0f, dot, pi.w + c.w);
        key[t] = __float_as_uint(d2 + 16.0f);
    }

    unsigned km = 0xFFFFFFFFu;
    #pragma unroll
    for (int t = 0; t < 32; ++t) km = min(km, key[t]);

    unsigned v = km;
    #pragma unroll
    for (int k = 2; k <= 64; k <<= 1) {
        #pragma unroll
        for (int j = k >> 1; j > 0; j >>= 1) {
            unsigned o = (unsigned)__shfl_xor((int)v, j, 64);
            bool up = ((lane & k) == 0);
            bool lower = ((lane & j) == 0);
            unsigned mn = min(v, o), mx = max(v, o);
            v = (up == lower) ? mn : mx;
        }
    }
    const unsigned T0 = (unsigned)__shfl((int)v, 15, 64);
    // >=16 candidates have key <= T0, and T0 >= true 16th-smallest
    // => {key <= T0} is a superset of the top-16.

    unsigned base = 0;
    #pragma unroll 1
    for (int t = 0; t < 32; ++t) {
        bool pred = key[t] <= T0;
        unsigned long long mask = __ballot(pred);
        if (mask) {
            unsigned prefix = __builtin_amdgcn_mbcnt_hi(
                (unsigned)(mask >> 32),
                __builtin_amdgcn_mbcnt_lo((unsigned)mask, 0));
            unsigned pos = base + prefix;
            if (pred && pos < CAP) {
                ckey[w][pos] = key[t];
                cidx[w][pos] = (unsigned)(t * 64 + lane);
            }
            base += (unsigned)__popcll(mask);
        }
    }
    __threadfence_block();
    const int m = (int)base;

    int* out = nbr + ((size_t)b * NPTS + i) * KNN;
    float ax = 0.f, ay = 0.f, az = 0.f;               // fused position sum

    if (m <= CAP) {
        unsigned k0 = (lane < m) ? ckey[w][lane] : 0xFFFFFFFFu;
        unsigned k1 = (lane + 64 < m) ? ckey[w][lane + 64] : 0xFFFFFFFFu;
        int r0 = 0, r1 = 0;
        if (m <= 64) {
            #pragma unroll 1
            for (int jj = 0; jj < m; ++jj) {
                unsigned kj = ckey[w][jj];
                r0 += (kj < k0) || (kj == k0 && jj < lane);
            }
        } else {
            #pragma unroll 1
            for (int jj = 0; jj < m; ++jj) {
                unsigned kj = ckey[w][jj];
                r0 += (kj < k0) || (kj == k0 && jj < lane);
                r1 += (kj < k1) || (kj == k1 && jj < lane + 64);
            }
        }
        if (lane < m && r0 < KNN) {
            unsigned j = cidx[w][lane];
            out[r0] = (int)j;
            float4 q = pts[j]; ax += q.x; ay += q.y; az += q.z;
        }
        if (m > 64 && lane + 64 < m && r1 < KNN) {
            unsigned j = cidx[w][lane + 64];
            out[r1] = (int)j;
            float4 q = pts[j]; ax += q.x; ay += q.y; az += q.z;
        }
    } else {
        // exact fallback (never taken w/ random data; correctness only)
        unsigned T = 0;
        #pragma unroll 1
        for (int bit = 31; bit >= 0; --bit) {
            unsigned trial = T | (1u << bit);
            int cnt = 0;
            #pragma unroll
            for (int t = 0; t < 32; ++t) cnt += (key[t] < trial);
            #pragma unroll
            for (int off = 32; off; off >>= 1)
                cnt += __shfl_xor(cnt, off, 64);
            if (cnt < KNN) T = trial;
        }
        unsigned bs = 0;
        #pragma unroll 1
        for (int t = 0; t < 32; ++t) {
            bool p1 = key[t] < T;
            unsigned long long mask = __ballot(p1);
            if (mask) {
                unsigned prefix = __builtin_amdgcn_mbcnt_hi(
                    (unsigned)(mask >> 32),
                    __builtin_amdgcn_mbcnt_lo((unsigned)mask, 0));
                if (p1) {
                    out[bs + prefix] = t * 64 + lane;
                    float4 q = pts[t * 64 + lane];
                    ax += q.x; ay += q.y; az += q.z;
                }
                bs += (unsigned)__popcll(mask);
            }
        }
        #pragma unroll 1
        for (int t = 0; t < 32 && bs < KNN; ++t) {
            bool p2 = key[t] == T;
            unsigned long long mask = __ballot(p2);
            if (mask) {
                unsigned prefix = __builtin_amdgcn_mbcnt_hi(
                    (unsigned)(mask >> 32),
                    __builtin_amdgcn_mbcnt_lo((unsigned)mask, 0));
                unsigned pos = bs + prefix;
                if (p2 && pos < KNN) {
                    out[pos] = t * 64 + lane;
                    float4 q = pts[t * 64 + lane];
                    ax += q.x; ay += q.y; az += q.z;
                }
                bs += (unsigned)__popcll(mask);
            }
        }
    }

    // wave-reduce the position sums; lane 0 writes aggpc
    #pragma unroll
    for (int off = 32; off; off >>= 1) {
        ax += __shfl_xor(ax, off, 64);
        ay += __shfl_xor(ay, off, 64);
        az += __shfl_xor(az, off, 64);
    }
    if (lane == 0)
        aggpc[(size_t)b * NPTS + i] = make_float4(ax, ay, az, 0.f);
}

// ---------------------------------------------------------------------------
// Layer 1: 3 -> 128 on precomputed aggpc. Thread per (p, h). Gather-free.
// ---------------------------------------------------------------------------
__global__ __launch_bounds__(256) void layer1_kernel(
    const float* __restrict__ pc, const float4* __restrict__ aggpc,
    const float* __restrict__ W1r, const float* __restrict__ b1,
    const float* __restrict__ W1s, unsigned short* __restrict__ x1)
{
    int gid = blockIdx.x * 256 + threadIdx.x;     // < 32768*128
    int p = gid >> 7;
    int h = gid & 127;
    float4 a = aggpc[p];
    float xx = pc[(size_t)p * 3 + 0];
    float xy = pc[(size_t)p * 3 + 1];
    float xz = pc[(size_t)p * 3 + 2];
    float acc = b1[h];
    acc += W1r[h * 3 + 0] * a.x + W1r[h * 3 + 1] * a.y + W1r[h * 3 + 2] * a.z;
    acc += W1s[h * 3 + 0] * xx + W1s[h * 3 + 1] * xy + W1s[h * 3 + 2] * xz;
    x1[gid] = f2bf(fmaxf(acc, 0.f));
}

// ---------------------------------------------------------------------------
// Weight conversion: 4 x [128x128] f32 -> bf16.
// ---------------------------------------------------------------------------
__global__ __launch_bounds__(256) void wcvt_kernel(
    const float* __restrict__ a, const float* __restrict__ b,
    const float* __restrict__ c, const float* __restrict__ d,
    unsigned short* __restrict__ out)
{
    int g = blockIdx.x * 256 + threadIdx.x;       // < 65536
    int m = g >> 14;
    const float* s = (m == 0) ? a : (m == 1) ? b : (m == 2) ? c : d;
    out[g] = f2bf(s[g & 16383]);
}

// ---------------------------------------------------------------------------
// Fused gather + GraphConv via bf16 MFMA.
// Block 512 thr = 8 waves, tile 64 points x 128 h.
// Gather task map v2: wave = 4 points x 16 channel-chunks, so each
// neighbor-row read is 16 consecutive lanes x 16B = contiguous 256 B
// (4x fewer L2 transactions than the R6 64-rows-per-wave map).
// MFMA: wave (32 pt x 32 h); A from LDS/global, B=W rows from global (L1).
// Layouts [measured m89/m91]: A[m=lane&15][k=quad*8+j]; B^T same;
// D: col=lane&15, row=quad*4+reg.
// ---------------------------------------------------------------------------
template <bool RELU, bool OUT_BF16>
__global__ __launch_bounds__(512) void conv_fused(
    const unsigned short* __restrict__ x, const int* __restrict__ nbr,
    const unsigned short* __restrict__ Wr, const unsigned short* __restrict__ Ws,
    const float* __restrict__ bias, void* __restrict__ outv)
{
    __shared__ __align__(16) unsigned short aggs[64][136];   // 17.4 KB
    __shared__ int nbrs[64][17];                             // 4.4 KB
    const int p0 = blockIdx.x * 64;                          // global point base
    const int bt = p0 >> 11;                                 // batch
    const unsigned short* xb = x + ((size_t)bt << 11) * HID; // batch-local rows

    // ---- stage nbr into LDS (coalesced) -----------------------------------
    for (int e = threadIdx.x; e < 64 * KNN; e += 512)
        nbrs[e >> 4][e & 15] = nbr[(size_t)p0 * KNN + e];
    __syncthreads();

    // ---- cooperative gather-sum -> bf16 agg tile --------------------------
    // task = (pt, c8): c8 = low 4 bits -> 16 lanes span one row contiguously.
    #pragma unroll
    for (int it = 0; it < 2; ++it) {
        int task = it * 512 + threadIdx.x;        // 0..1023
        int c8 = task & 15, pt = task >> 4;       // pt 0..63
        const unsigned short* base = xb + c8 * 8;
        float s[8] = {0, 0, 0, 0, 0, 0, 0, 0};
        #pragma unroll
        for (int t = 0; t < KNN; ++t) {
            int j = nbrs[pt][t];
            uint4 v = *(const uint4*)(base + (size_t)j * HID);
            s[0] += bflo(v.x); s[1] += bfhi(v.x);
            s[2] += bflo(v.y); s[3] += bfhi(v.y);
            s[4] += bflo(v.z); s[5] += bfhi(v.z);
            s[6] += bflo(v.w); s[7] += bfhi(v.w);
        }
        uint4 ov;
        ov.x = (unsigned)f2bf(s[0]) | ((unsigned)f2bf(s[1]) << 16);
        ov.y = (unsigned)f2bf(s[2]) | ((unsigned)f2bf(s[3]) << 16);
        ov.z = (unsigned)f2bf(s[4]) | ((unsigned)f2bf(s[5]) << 16);
        ov.w = (unsigned)f2bf(s[6]) | ((unsigned)f2bf(s[7]) << 16);
        *(uint4*)&aggs[pt][c8 * 8] = ov;
    }
    __syncthreads();

    // ---- MFMA: wave tile 32 pts x 32 h ------------------------------------
    const int wv = threadIdx.x >> 6;
    const int lane = threadIdx.x & 63;
    const int ptw = (wv & 1) * 32;                // 0 / 32
    const int h0w = (wv >> 1) * 32;               // 0 / 32 / 64 / 96
    const int row = lane & 15;
    const int quad = lane >> 4;

    f32x4 acc[2][2];
    #pragma unroll
    for (int i = 0; i < 2; ++i)
        #pragma unroll
        for (int n = 0; n < 2; ++n) acc[i][n] = (f32x4){0, 0, 0, 0};

    // agg @ Wr^T
    #pragma unroll
    for (int kc = 0; kc < 4; ++kc) {
        bf16x8 a0 = *(const bf16x8*)&aggs[ptw + row][quad * 8 + kc * 32];
        bf16x8 a1 = *(const bf16x8*)&aggs[ptw + 16 + row][quad * 8 + kc * 32];
        #pragma unroll
        for (int n = 0; n < 2; ++n) {
            bf16x8 bb = *(const bf16x8*)&Wr[(size_t)(h0w + n * 16 + row) * HID
                                            + quad * 8 + kc * 32];
            acc[0][n] = __builtin_amdgcn_mfma_f32_16x16x32_bf16(a0, bb, acc[0][n], 0, 0, 0);
            acc[1][n] = __builtin_amdgcn_mfma_f32_16x16x32_bf16(a1, bb, acc[1][n], 0, 0, 0);
        }
    }
    // x @ Ws^T
    const unsigned short* xr0 = x + (size_t)(p0 + ptw + row) * HID + quad * 8;
    const unsigned short* xr1 = xr0 + 16 * HID;
    #pragma unroll
    for (int kc = 0; kc < 4; ++kc) {
        bf16x8 a0 = *(const bf16x8*)(xr0 + kc * 32);
        bf16x8 a1 = *(const bf16x8*)(xr1 + kc * 32);
        #pragma unroll
        for (int n = 0; n < 2; ++n) {
            bf16x8 bb = *(const bf16x8*)&Ws[(size_t)(h0w + n * 16 + row) * HID
                                            + quad * 8 + kc * 32];
            acc[0][n] = __builtin_amdgcn_mfma_f32_16x16x32_bf16(a0, bb, acc[0][n], 0, 0, 0);
            acc[1][n] = __builtin_amdgcn_mfma_f32_16x16x32_bf16(a1, bb, acc[1][n], 0, 0, 0);
        }
    }

    // ---- epilogue ---------------------------------------------------------
    #pragma unroll
    for (int n = 0; n < 2; ++n) {
        float bh = bias[h0w + n * 16 + row];
        #pragma unroll
        for (int i = 0; i < 2; ++i) {
            #pragma unroll
            for (int r = 0; r < 4; ++r) {
                int pp = p0 + ptw + i * 16 + quad * 4 + r;
                float vv = acc[i][n][r] + bh;
                if (RELU) vv = fmaxf(vv, 0.f);
                if (OUT_BF16)
                    ((unsigned short*)outv)[(size_t)pp * HID + h0w + n * 16 + row] = f2bf(vv);
                else
                    ((float*)outv)[(size_t)pp * HID + h0w + n * 16 + row] = vv;
            }
        }
    }
}

// ---------------------------------------------------------------------------
extern "C" void kernel_launch(void* const* d_in, const int* in_sizes, int n_in,
                              void* d_out, int out_size, void* d_ws, size_t ws_size,
                              hipStream_t stream)
{
    const float* pc  = (const float*)d_in[0];
    const float* W1r = (const float*)d_in[1];
    const float* b1  = (const float*)d_in[2];
    const float* W1s = (const float*)d_in[3];
    const float* W2r = (const float*)d_in[4];
    const float* b2  = (const float*)d_in[5];
    const float* W2s = (const float*)d_in[6];
    const float* W3r = (const float*)d_in[7];
    const float* b3  = (const float*)d_in[8];
    const float* W3s = (const float*)d_in[9];
    float* out = (float*)d_out;

    char* ws = (char*)d_ws;
    const size_t MB = 1024 * 1024;
    int*            nbr   = (int*)ws;                             // 2 MB
    float4*         aggpc = (float4*)(ws + 2 * MB);               // 512 KB
    unsigned short* x1    = (unsigned short*)(ws + 3 * MB);       // 8.39 MB
    unsigned short* x2    = (unsigned short*)(ws + 3 * MB + 8388608);
    unsigned short* wbf   = (unsigned short*)(ws + 3 * MB + 2 * 8388608);
    unsigned short* w2r = wbf;
    unsigned short* w2s = wbf + 16384;
    unsigned short* w3r = wbf + 32768;
    unsigned short* w3s = wbf + 49152;

    const int NPOINTS = BATCH * NPTS;                             // 32768

    knn_kernel<<<NPOINTS / RPB, 512, 0, stream>>>(pc, nbr, aggpc);
    layer1_kernel<<<NPOINTS * HID / 256, 256, 0, stream>>>(
        pc, aggpc, W1r, b1, W1s, x1);
    wcvt_kernel<<<256, 256, 0, stream>>>(W2r, W2s, W3r, W3s, wbf);

    conv_fused<true, true><<<NPOINTS / 64, 512, 0, stream>>>(
        x1, nbr, w2r, w2s, b2, x2);
    conv_fused<false, false><<<NPOINTS / 64, 512, 0, stream>>>(
        x2, nbr, w3r, w3s, b3, out);
}